// Round 10
// baseline (123.451 us; speedup 1.0000x reference)
//
#include <hip/hip_runtime.h>
#include <math.h>

#define NBATCH 8192
#define NNEI 256
#define NROLE 3
#define NHID 32
#define NDIM 6
// 48B record stride: record p's b128 lands in 16B-bank-group (3p mod 8) — a
// perfect permutation over all 8 groups -> near-conflict-free for b128/b64/b32.
#define SSTRIDE 12

typedef float v2f __attribute__((ext_vector_type(2)));
typedef unsigned long long ull;

// Compiler-fenced lgkm-only barrier (CK "block_sync_lds" idiom): unlike
// __syncthreads(), does NOT drain vmcnt — any global loads stay in flight.
// imm 0xC07F: vmcnt=63, expcnt=7, lgkmcnt=0.
__device__ __forceinline__ void barrier_lds_only() {
  __asm__ __volatile__("" ::: "memory");
  __builtin_amdgcn_s_waitcnt(0xC07F);
  __builtin_amdgcn_s_barrier();
  __asm__ __volatile__("" ::: "memory");
}

// DPP lane-shift move (VALU-only, no DS pipe, no address setup).
// bound_ctrl=true -> out-of-range source lanes produce 0 (safe for sums).
template <int CTRL>
__device__ __forceinline__ float dppmov(float x) {
  return __int_as_float(__builtin_amdgcn_update_dpp(
      0, __float_as_int(x), CTRL, 0xF, 0xF, true));
}

// 64-lane sum via DPP prefix reduction; lane 63 holds the full total.
__device__ __forceinline__ float wavesum_dpp(float v) {
  v += dppmov<0x111>(v);  // row_shr:1
  v += dppmov<0x112>(v);  // row_shr:2
  v += dppmov<0x114>(v);  // row_shr:4
  v += dppmov<0x118>(v);  // row_shr:8
  v += dppmov<0x142>(v);  // row_bcast:15
  v += dppmov<0x143>(v);  // row_bcast:31
  return v;               // lane 63 = total
}
__device__ __forceinline__ float total63(float v) {
  return __int_as_float(
      __builtin_amdgcn_readlane(__float_as_int(wavesum_dpp(v)), 63));
}

// MLP score via packed-f32 pairs (v_pk_fma_f32): Linear(6,32)->ReLU->Linear(32,1).
// Weight pointers MUST be wave-uniform (readfirstlane'd role) so weight reads
// stay s_load scalar traffic — R5 showed losing this costs 4x.
__device__ __forceinline__ float mlp_score(const float x0, const float x1,
                                           const float x2, const float x3,
                                           const float x4, const float x5,
                                           const float* __restrict__ w1,
                                           const float* __restrict__ bb,
                                           const float* __restrict__ w2,
                                           const float b2v) {
  const float x[NDIM] = {x0, x1, x2, x3, x4, x5};
  v2f ac0 = {0.f, 0.f}, ac1 = {0.f, 0.f}, ac2 = {0.f, 0.f}, ac3 = {0.f, 0.f};
#pragma unroll
  for (int h = 0; h < NHID; h += 8) {
    v2f a0 = *(const v2f*)(bb + h + 0);
    v2f a1 = *(const v2f*)(bb + h + 2);
    v2f a2 = *(const v2f*)(bb + h + 4);
    v2f a3 = *(const v2f*)(bb + h + 6);
#pragma unroll
    for (int d = 0; d < NDIM; ++d) {
      const float xv = x[d];
      const v2f xv2 = {xv, xv};
      const float* wc = w1 + d * NHID + h;  // uniform addr -> s_load
      a0 += xv2 * (*(const v2f*)(wc + 0));  // -ffp-contract -> v_pk_fma_f32
      a1 += xv2 * (*(const v2f*)(wc + 2));
      a2 += xv2 * (*(const v2f*)(wc + 4));
      a3 += xv2 * (*(const v2f*)(wc + 6));
    }
    a0.x = fmaxf(a0.x, 0.f); a0.y = fmaxf(a0.y, 0.f);
    a1.x = fmaxf(a1.x, 0.f); a1.y = fmaxf(a1.y, 0.f);
    a2.x = fmaxf(a2.x, 0.f); a2.y = fmaxf(a2.y, 0.f);
    a3.x = fmaxf(a3.x, 0.f); a3.y = fmaxf(a3.y, 0.f);
    ac0 += a0 * (*(const v2f*)(w2 + h + 0));
    ac1 += a1 * (*(const v2f*)(w2 + h + 2));
    ac2 += a2 * (*(const v2f*)(w2 + h + 4));
    ac3 += a3 * (*(const v2f*)(w2 + h + 6));
  }
  const v2f st = (ac0 + ac1) + (ac2 + ac3);
  return b2v + st.x + st.y;
}

// 384-thread WGs = TWO independent batches side-by-side: waves 0-2 run batch
// 2k exactly like the 118.76us kernel's waves 0-2, waves 3-5 run batch 2k+1.
// Identical per-wave code and serial path; one shared lgkm-barrier; grid
// halves to 4096 -> CP dispatch-conveyor time (~26.5us at the measured ~310
// WG/us ceiling, 70% of the 37.5us kernel) halves. Occupancy: 5 WGs/CU
// (wave cap) x 6 waves = 30 waves/CU, same as before; LDS 25.7KB -> cap 6.
// Softmax max-subtraction cancels exactly in mf = sum(e*tw*v)/sum(e*tw)
// (exp(-m) divides out; only the 1e-8 epsilons break it, ~1e-10 relative;
// scores are O(1..12) so exp cannot overflow) — so we skip the max chain.
__global__ __launch_bounds__(384) void hmf_main(
    const float* __restrict__ states,
    const int* __restrict__ roles,
    const int* __restrict__ maskp,   // bool arrives as int32
    const float* __restrict__ trust,
    const float* __restrict__ W1,    // [R][D][H]
    const float* __restrict__ b1,    // [R][H]
    const float* __restrict__ W2,    // [R][H]
    const float* __restrict__ b2g,   // [R]
    float* __restrict__ out) {
  const int tid = threadIdx.x;
  const int wave = tid >> 6;            // 0..5
  const int lane = tid & 63;
  const int q = (wave >= 3) ? 1 : 0;    // batch-half of this wave
  const int wv3 = wave - q * 3;         // 0..2 within the half
  const int b = blockIdx.x * 2 + q;

  __shared__ float ssort[2][NNEI * SSTRIDE];    // 24 KB; half q, chunk c owns [64c,64c+64)
  __shared__ alignas(16) int scnt4[2][4];       // packed c0|c1<<8|c2<<16 per chunk

  const size_t rowb = (size_t)b * NNEI;
  float* const ss = &ssort[q][0];

  // ---- phase 1: coalesced loads, per-role ballots, per-chunk sorted scatter ----
  // chunk A = wv3; chunk B = 3 (wv3==0 only). Issue ALL loads before ballots.
  const size_t idxA = rowb + (size_t)(wv3 * 64 + lane);
  const int roleA = roles[idxA];
  const int maskA = maskp[idxA];
  const float twA = trust[idxA];
  const float* spA = states + idxA * (size_t)NDIM;
  const float2 aA = *(const float2*)(spA);
  const float2 aB = *(const float2*)(spA + 2);
  const float2 aC = *(const float2*)(spA + 4);

  const bool have2 = (wv3 == 0);
  int roleB = 0, maskB = 0;
  float twB = 0.f;
  float2 bA = {0.f, 0.f}, bB = {0.f, 0.f}, bC = {0.f, 0.f};
  if (have2) {
    const size_t idxB = rowb + (size_t)(192 + lane);
    roleB = roles[idxB];
    maskB = maskp[idxB];
    twB = trust[idxB];
    const float* spB = states + idxB * (size_t)NDIM;
    bA = *(const float2*)(spB);
    bB = *(const float2*)(spB + 2);
    bC = *(const float2*)(spB + 4);
  }

  {  // chunk A (c = wv3)
    const bool active = (maskA != 0);
    const ull bal0 = __ballot(active && (roleA == 0));
    const ull bal1 = __ballot(active && (roleA == 1));
    const ull bal2 = __ballot(active && (roleA == 2));
    const int c0 = __popcll(bal0);
    const int c1 = __popcll(bal1);
    const int c2 = __popcll(bal2);
    if (lane == 0) scnt4[q][wv3] = c0 | (c1 << 8) | (c2 << 16);
    if (active) {
      const ull mybal = (roleA == 0) ? bal0 : (roleA == 1) ? bal1 : bal2;
      const int rank = __popcll(mybal & ((1ull << lane) - 1ull));
      const int pre = ((roleA >= 1) ? c0 : 0) + ((roleA >= 2) ? c1 : 0);
      const int pos = wv3 * 64 + pre + rank;  // chunk-private region
      float* dst = ss + pos * SSTRIDE;
      *(float4*)dst = make_float4(aA.x, aA.y, aB.x, aB.y);
      *(float4*)(dst + 4) = make_float4(aC.x, aC.y, twA, 0.f);
    }
  }
  if (have2) {  // chunk B (c = 3), wv3==0 only — ballots are whole-wave here
    const bool active = (maskB != 0);
    const ull bal0 = __ballot(active && (roleB == 0));
    const ull bal1 = __ballot(active && (roleB == 1));
    const ull bal2 = __ballot(active && (roleB == 2));
    const int c0 = __popcll(bal0);
    const int c1 = __popcll(bal1);
    const int c2 = __popcll(bal2);
    if (lane == 0) scnt4[q][3] = c0 | (c1 << 8) | (c2 << 16);
    if (active) {
      const ull mybal = (roleB == 0) ? bal0 : (roleB == 1) ? bal1 : bal2;
      const int rank = __popcll(mybal & ((1ull << lane) - 1ull));
      const int pre = ((roleB >= 1) ? c0 : 0) + ((roleB >= 2) ? c1 : 0);
      const int pos = 192 + pre + rank;
      float* dst = ss + pos * SSTRIDE;
      *(float4*)dst = make_float4(bA.x, bA.y, bB.x, bB.y);
      *(float4*)(dst + 4) = make_float4(bC.x, bC.y, twB, 0.f);
    }
  }
  barrier_lds_only();  // the ONLY barrier

  // ---- phase 3: wave (q, r=wv3) handles role r of batch b ----
  {
    const int r = __builtin_amdgcn_readfirstlane(wv3);
    const int4 scv = *(const int4*)&scnt4[q][0];  // single ds_read_b128
    int cwv[4], prw[4];
#pragma unroll
    for (int w = 0; w < 4; ++w) {
      const int pk = __builtin_amdgcn_readfirstlane((&scv.x)[w]);
      const int a0 = pk & 0xFF;
      const int a1 = (pk >> 8) & 0xFF;
      const int a2 = (pk >> 16) & 0xFF;
      cwv[w] = (r == 0) ? a0 : (r == 1) ? a1 : a2;
      prw[w] = ((r >= 1) ? a0 : 0) + ((r >= 2) ? a1 : 0);
    }
    const int acc0 = cwv[0];
    const int acc1 = acc0 + cwv[1];
    const int acc2 = acc1 + cwv[2];
    const int cnt = acc2 + cwv[3];

    const float* w1 = W1 + r * (NDIM * NHID);
    const float* bb = b1 + r * NHID;
    const float* w2 = W2 + r * NHID;
    const float b2v = b2g[r];

    float q0, q1, q2, q3, q4, q5, q6, q7;  // {Se, Set, Sd0..Sd5}

    if (cnt <= 64) {
      // ---- FAST PATH (P ~ 1 - 1e-4): single chunk, static control flow ----
      const bool act = lane < cnt;
      const bool s1 = lane >= acc0;
      const bool s2 = lane >= acc1;
      const bool s3 = lane >= acc2;
      int sub = s1 ? acc0 : 0; sub = s2 ? acc1 : sub; sub = s3 ? acc2 : sub;
      int wb = s1 ? 64 : 0;    wb = s2 ? 128 : wb;    wb = s3 ? 192 : wb;
      int pr = s1 ? prw[1] : prw[0]; pr = s2 ? prw[2] : pr; pr = s3 ? prw[3] : pr;
      int pos = wb + pr + (lane - sub);
      pos = (pos > NNEI - 1) ? (NNEI - 1) : pos;  // inactive lanes may overrun
      const float* s = ss + pos * SSTRIDE;
      float4 v4 = *(const float4*)s;
      float4 vb = *(const float4*)(s + 4);
      float tw = vb.z;
      if (!act) {  // select-gate: garbage slots may hold NaN
        v4 = make_float4(0.f, 0.f, 0.f, 0.f);
        vb = make_float4(0.f, 0.f, 0.f, 0.f);
        tw = 0.f;
      }
      const float sc = mlp_score(v4.x, v4.y, v4.z, v4.w, vb.x, vb.y, w1, bb, w2, b2v);
      const float e = act ? __expf(sc) : 0.f;
      const float et = e * tw;
      q0 = e; q1 = et;
      q2 = et * v4.x; q3 = et * v4.y; q4 = et * v4.z;
      q5 = et * v4.w; q6 = et * vb.x; q7 = et * vb.y;
    } else {
      // ---- SLOW PATH (cold, ~3 lists in 24576): dynamic chunk loop ----
      q0 = q1 = q2 = q3 = q4 = q5 = q6 = q7 = 0.f;
      const int nch = (cnt + 63) >> 6;
      for (int c = 0; c < nch; ++c) {
        const int jj = c * 64 + lane;
        const bool act = jj < cnt;
        const bool s1 = jj >= acc0;
        const bool s2 = jj >= acc1;
        const bool s3 = jj >= acc2;
        int sub = s1 ? acc0 : 0; sub = s2 ? acc1 : sub; sub = s3 ? acc2 : sub;
        int wb = s1 ? 64 : 0;    wb = s2 ? 128 : wb;    wb = s3 ? 192 : wb;
        int pr = s1 ? prw[1] : prw[0]; pr = s2 ? prw[2] : pr; pr = s3 ? prw[3] : pr;
        int pos = wb + pr + (jj - sub);
        pos = (pos > NNEI - 1) ? (NNEI - 1) : pos;
        pos = (pos < 0) ? 0 : pos;
        const float* s = ss + pos * SSTRIDE;
        float4 v4 = *(const float4*)s;
        float4 vb = *(const float4*)(s + 4);
        float tw = vb.z;
        if (!act) {
          v4 = make_float4(0.f, 0.f, 0.f, 0.f);
          vb = make_float4(0.f, 0.f, 0.f, 0.f);
          tw = 0.f;
        }
        const float sc = mlp_score(v4.x, v4.y, v4.z, v4.w, vb.x, vb.y, w1, bb, w2, b2v);
        const float e = act ? __expf(sc) : 0.f;
        const float et = e * tw;
        q0 += e; q1 += et;
        q2 = fmaf(et, v4.x, q2); q3 = fmaf(et, v4.y, q3);
        q4 = fmaf(et, v4.z, q4); q5 = fmaf(et, v4.w, q5);
        q6 = fmaf(et, vb.x, q6); q7 = fmaf(et, vb.y, q7);
      }
    }

    // ---- reduction: 8 independent DPP prefix-sums (VALU-only, no DS pipe) ----
    const float Se  = total63(q0);
    const float Set = total63(q1);
    const float T2  = total63(q2);
    const float T3  = total63(q3);
    const float T4  = total63(q4);
    const float T5  = total63(q5);
    const float T6  = total63(q6);
    const float T7  = total63(q7);

    const float denom = Se + 1e-8f;
    const float ws = fmaxf(Set / denom, 1e-8f);
    const float scale = 1.0f / (denom * ws);  // one div (uniform) vs 12 lane-divs
    if (lane >= 2 && lane < 8) {
      float num = T2;
      num = (lane == 3) ? T3 : num;
      num = (lane == 4) ? T4 : num;
      num = (lane == 5) ? T5 : num;
      num = (lane == 6) ? T6 : num;
      num = (lane == 7) ? T7 : num;
      out[(size_t)b * (NROLE * NDIM) + r * NDIM + (lane - 2)] = num * scale;
    }
  }
}

extern "C" void kernel_launch(void* const* d_in, const int* in_sizes, int n_in,
                              void* d_out, int out_size, void* d_ws, size_t ws_size,
                              hipStream_t stream) {
  const float* states = (const float*)d_in[0];
  const int* roles = (const int*)d_in[1];
  const int* maskp = (const int*)d_in[2];
  const float* trust = (const float*)d_in[3];
  const float* W1 = (const float*)d_in[4];
  const float* b1 = (const float*)d_in[5];
  const float* W2 = (const float*)d_in[6];
  const float* b2 = (const float*)d_in[7];
  float* out = (float*)d_out;

  hmf_main<<<NBATCH / 2, 384, 0, stream>>>(states, roles, maskp, trust, W1, b1, W2, b2, out);
}

// Round 11
// 117.711 us; speedup vs baseline: 1.0488x; 1.0488x over previous
//
#include <hip/hip_runtime.h>
#include <math.h>

#define NBATCH 8192
#define NNEI 256
#define NROLE 3
#define NHID 32
#define NDIM 6
// 48B record stride: record p's b128 lands in 16B-bank-group (3p mod 8) — a
// perfect permutation over all 8 groups -> near-conflict-free for b128/b64/b32.
#define SSTRIDE 12

typedef float v2f __attribute__((ext_vector_type(2)));
typedef unsigned long long ull;

// Compiler-fenced lgkm-only barrier (CK "block_sync_lds" idiom): unlike
// __syncthreads(), does NOT drain vmcnt — any global loads stay in flight.
// imm 0xC07F: vmcnt=63, expcnt=7, lgkmcnt=0.
__device__ __forceinline__ void barrier_lds_only() {
  __asm__ __volatile__("" ::: "memory");
  __builtin_amdgcn_s_waitcnt(0xC07F);
  __builtin_amdgcn_s_barrier();
  __asm__ __volatile__("" ::: "memory");
}

// DPP lane-shift move (VALU-only, no DS pipe, no address setup).
// bound_ctrl=true -> out-of-range source lanes produce 0 (safe for sums).
template <int CTRL>
__device__ __forceinline__ float dppmov(float x) {
  return __int_as_float(__builtin_amdgcn_update_dpp(
      0, __float_as_int(x), CTRL, 0xF, 0xF, true));
}

// 64-lane sum via DPP prefix reduction: after row_shr 1/2/4/8 each 16-row's
// lane15 holds the row total; row_bcast15 then row_bcast31 accumulate rows.
// Lane 63 holds the full total. Replaces 6 ds_bpermute levels (DS pipe +
// ~26cy/level latency) with 6 VALU adds.
__device__ __forceinline__ float wavesum_dpp(float v) {
  v += dppmov<0x111>(v);  // row_shr:1
  v += dppmov<0x112>(v);  // row_shr:2
  v += dppmov<0x114>(v);  // row_shr:4
  v += dppmov<0x118>(v);  // row_shr:8
  v += dppmov<0x142>(v);  // row_bcast:15
  v += dppmov<0x143>(v);  // row_bcast:31
  return v;               // lane 63 = total
}
__device__ __forceinline__ float total63(float v) {
  return __int_as_float(
      __builtin_amdgcn_readlane(__float_as_int(wavesum_dpp(v)), 63));
}

// MLP score via packed-f32 pairs (v_pk_fma_f32): Linear(6,32)->ReLU->Linear(32,1).
// Weight pointers MUST be wave-uniform (readfirstlane'd role) so weight reads
// stay s_load scalar traffic — R5 showed losing this costs 4x.
__device__ __forceinline__ float mlp_score(const float x0, const float x1,
                                           const float x2, const float x3,
                                           const float x4, const float x5,
                                           const float* __restrict__ w1,
                                           const float* __restrict__ bb,
                                           const float* __restrict__ w2,
                                           const float b2v) {
  const float x[NDIM] = {x0, x1, x2, x3, x4, x5};
  v2f ac0 = {0.f, 0.f}, ac1 = {0.f, 0.f}, ac2 = {0.f, 0.f}, ac3 = {0.f, 0.f};
#pragma unroll
  for (int h = 0; h < NHID; h += 8) {
    v2f a0 = *(const v2f*)(bb + h + 0);
    v2f a1 = *(const v2f*)(bb + h + 2);
    v2f a2 = *(const v2f*)(bb + h + 4);
    v2f a3 = *(const v2f*)(bb + h + 6);
#pragma unroll
    for (int d = 0; d < NDIM; ++d) {
      const float xv = x[d];
      const v2f xv2 = {xv, xv};
      const float* wc = w1 + d * NHID + h;  // uniform addr -> s_load
      a0 += xv2 * (*(const v2f*)(wc + 0));  // -ffp-contract -> v_pk_fma_f32
      a1 += xv2 * (*(const v2f*)(wc + 2));
      a2 += xv2 * (*(const v2f*)(wc + 4));
      a3 += xv2 * (*(const v2f*)(wc + 6));
    }
    a0.x = fmaxf(a0.x, 0.f); a0.y = fmaxf(a0.y, 0.f);
    a1.x = fmaxf(a1.x, 0.f); a1.y = fmaxf(a1.y, 0.f);
    a2.x = fmaxf(a2.x, 0.f); a2.y = fmaxf(a2.y, 0.f);
    a3.x = fmaxf(a3.x, 0.f); a3.y = fmaxf(a3.y, 0.f);
    ac0 += a0 * (*(const v2f*)(w2 + h + 0));
    ac1 += a1 * (*(const v2f*)(w2 + h + 2));
    ac2 += a2 * (*(const v2f*)(w2 + h + 4));
    ac3 += a3 * (*(const v2f*)(w2 + h + 6));
  }
  const v2f st = (ac0 + ac1) + (ac2 + ac3);
  return b2v + st.x + st.y;
}

// 192-thread blocks (3 waves): wave r owns role r in phase 3 -> no idle wave.
// Wave 0 additionally handles chunk 3 in phase 1 (loads issued together, so
// latency overlaps; waves 1-2 just reach the barrier early).
// Softmax max-subtraction cancels exactly in mf = sum(e*tw*v)/sum(e*tw)
// (exp(-m) divides out; only the 1e-8 epsilons break it, ~1e-10 relative;
// scores are O(1..12) so exp cannot overflow) — so we skip the max chain.
__global__ __launch_bounds__(192) void hmf_main(
    const float* __restrict__ states,
    const int* __restrict__ roles,
    const int* __restrict__ maskp,   // bool arrives as int32
    const float* __restrict__ trust,
    const float* __restrict__ W1,    // [R][D][H]
    const float* __restrict__ b1,    // [R][H]
    const float* __restrict__ W2,    // [R][H]
    const float* __restrict__ b2g,   // [R]
    float* __restrict__ out) {
  const int b = blockIdx.x;
  const int tid = threadIdx.x;
  const int wave = tid >> 6;   // 0..2
  const int lane = tid & 63;

  __shared__ float ssort[NNEI * SSTRIDE];       // 12 KB; chunk c owns [64c,64c+64)
  __shared__ alignas(16) int scnt4[4];          // packed c0|c1<<8|c2<<16 per chunk

  const size_t rowb = (size_t)b * NNEI;

  // ---- phase 1: coalesced loads, per-role ballots, per-chunk sorted scatter ----
  // chunk A = wave; chunk B = 3 (wave 0 only). Issue ALL loads before ballots.
  const size_t idxA = rowb + (size_t)(wave * 64 + lane);
  const int roleA = roles[idxA];
  const int maskA = maskp[idxA];
  const float twA = trust[idxA];
  const float* spA = states + idxA * (size_t)NDIM;
  const float2 aA = *(const float2*)(spA);
  const float2 aB = *(const float2*)(spA + 2);
  const float2 aC = *(const float2*)(spA + 4);

  const bool have2 = (wave == 0);
  int roleB = 0, maskB = 0;
  float twB = 0.f;
  float2 bA = {0.f, 0.f}, bB = {0.f, 0.f}, bC = {0.f, 0.f};
  if (have2) {
    const size_t idxB = rowb + (size_t)(192 + lane);
    roleB = roles[idxB];
    maskB = maskp[idxB];
    twB = trust[idxB];
    const float* spB = states + idxB * (size_t)NDIM;
    bA = *(const float2*)(spB);
    bB = *(const float2*)(spB + 2);
    bC = *(const float2*)(spB + 4);
  }

  {  // chunk A (c = wave)
    const bool active = (maskA != 0);
    const ull bal0 = __ballot(active && (roleA == 0));
    const ull bal1 = __ballot(active && (roleA == 1));
    const ull bal2 = __ballot(active && (roleA == 2));
    const int c0 = __popcll(bal0);
    const int c1 = __popcll(bal1);
    const int c2 = __popcll(bal2);
    if (lane == 0) scnt4[wave] = c0 | (c1 << 8) | (c2 << 16);
    if (active) {
      const ull mybal = (roleA == 0) ? bal0 : (roleA == 1) ? bal1 : bal2;
      const int rank = __popcll(mybal & ((1ull << lane) - 1ull));
      const int pre = ((roleA >= 1) ? c0 : 0) + ((roleA >= 2) ? c1 : 0);
      const int pos = wave * 64 + pre + rank;  // chunk-private region
      float* dst = ssort + pos * SSTRIDE;
      *(float4*)dst = make_float4(aA.x, aA.y, aB.x, aB.y);
      *(float4*)(dst + 4) = make_float4(aC.x, aC.y, twA, 0.f);
    }
  }
  if (have2) {  // chunk B (c = 3), wave 0 only — ballots are whole-wave here
    const bool active = (maskB != 0);
    const ull bal0 = __ballot(active && (roleB == 0));
    const ull bal1 = __ballot(active && (roleB == 1));
    const ull bal2 = __ballot(active && (roleB == 2));
    const int c0 = __popcll(bal0);
    const int c1 = __popcll(bal1);
    const int c2 = __popcll(bal2);
    if (lane == 0) scnt4[3] = c0 | (c1 << 8) | (c2 << 16);
    if (active) {
      const ull mybal = (roleB == 0) ? bal0 : (roleB == 1) ? bal1 : bal2;
      const int rank = __popcll(mybal & ((1ull << lane) - 1ull));
      const int pre = ((roleB >= 1) ? c0 : 0) + ((roleB >= 2) ? c1 : 0);
      const int pos = 192 + pre + rank;
      float* dst = ssort + pos * SSTRIDE;
      *(float4*)dst = make_float4(bA.x, bA.y, bB.x, bB.y);
      *(float4*)(dst + 4) = make_float4(bC.x, bC.y, twB, 0.f);
    }
  }
  barrier_lds_only();  // the ONLY barrier

  // ---- phase 3: wave r handles role r across the 4 chunk-segments ----
  {
    const int r = __builtin_amdgcn_readfirstlane(wave);
    const int4 scv = *(const int4*)scnt4;  // single ds_read_b128
    int cwv[4], prw[4];
#pragma unroll
    for (int w = 0; w < 4; ++w) {
      const int pk = __builtin_amdgcn_readfirstlane((&scv.x)[w]);
      const int a0 = pk & 0xFF;
      const int a1 = (pk >> 8) & 0xFF;
      const int a2 = (pk >> 16) & 0xFF;
      cwv[w] = (r == 0) ? a0 : (r == 1) ? a1 : a2;
      prw[w] = ((r >= 1) ? a0 : 0) + ((r >= 2) ? a1 : 0);
    }
    const int acc0 = cwv[0];
    const int acc1 = acc0 + cwv[1];
    const int acc2 = acc1 + cwv[2];
    const int cnt = acc2 + cwv[3];

    const float* w1 = W1 + r * (NDIM * NHID);
    const float* bb = b1 + r * NHID;
    const float* w2 = W2 + r * NHID;
    const float b2v = b2g[r];

    float q0, q1, q2, q3, q4, q5, q6, q7;  // {Se, Set, Sd0..Sd5}

    if (cnt <= 64) {
      // ---- FAST PATH (P ~ 1 - 1e-4): single chunk, static control flow ----
      const bool act = lane < cnt;
      const bool s1 = lane >= acc0;
      const bool s2 = lane >= acc1;
      const bool s3 = lane >= acc2;
      int sub = s1 ? acc0 : 0; sub = s2 ? acc1 : sub; sub = s3 ? acc2 : sub;
      int wb = s1 ? 64 : 0;    wb = s2 ? 128 : wb;    wb = s3 ? 192 : wb;
      int pr = s1 ? prw[1] : prw[0]; pr = s2 ? prw[2] : pr; pr = s3 ? prw[3] : pr;
      int pos = wb + pr + (lane - sub);
      pos = (pos > NNEI - 1) ? (NNEI - 1) : pos;  // inactive lanes may overrun
      const float* s = ssort + pos * SSTRIDE;
      float4 v4 = *(const float4*)s;
      float4 vb = *(const float4*)(s + 4);
      float tw = vb.z;
      if (!act) {  // select-gate: garbage slots may hold NaN
        v4 = make_float4(0.f, 0.f, 0.f, 0.f);
        vb = make_float4(0.f, 0.f, 0.f, 0.f);
        tw = 0.f;
      }
      const float sc = mlp_score(v4.x, v4.y, v4.z, v4.w, vb.x, vb.y, w1, bb, w2, b2v);
      const float e = act ? __expf(sc) : 0.f;
      const float et = e * tw;
      q0 = e; q1 = et;
      q2 = et * v4.x; q3 = et * v4.y; q4 = et * v4.z;
      q5 = et * v4.w; q6 = et * vb.x; q7 = et * vb.y;
    } else {
      // ---- SLOW PATH (cold, ~3 lists in 24576): dynamic chunk loop ----
      q0 = q1 = q2 = q3 = q4 = q5 = q6 = q7 = 0.f;
      const int nch = (cnt + 63) >> 6;
      for (int c = 0; c < nch; ++c) {
        const int jj = c * 64 + lane;
        const bool act = jj < cnt;
        const bool s1 = jj >= acc0;
        const bool s2 = jj >= acc1;
        const bool s3 = jj >= acc2;
        int sub = s1 ? acc0 : 0; sub = s2 ? acc1 : sub; sub = s3 ? acc2 : sub;
        int wb = s1 ? 64 : 0;    wb = s2 ? 128 : wb;    wb = s3 ? 192 : wb;
        int pr = s1 ? prw[1] : prw[0]; pr = s2 ? prw[2] : pr; pr = s3 ? prw[3] : pr;
        int pos = wb + pr + (jj - sub);
        pos = (pos > NNEI - 1) ? (NNEI - 1) : pos;
        pos = (pos < 0) ? 0 : pos;
        const float* s = ssort + pos * SSTRIDE;
        float4 v4 = *(const float4*)s;
        float4 vb = *(const float4*)(s + 4);
        float tw = vb.z;
        if (!act) {
          v4 = make_float4(0.f, 0.f, 0.f, 0.f);
          vb = make_float4(0.f, 0.f, 0.f, 0.f);
          tw = 0.f;
        }
        const float sc = mlp_score(v4.x, v4.y, v4.z, v4.w, vb.x, vb.y, w1, bb, w2, b2v);
        const float e = act ? __expf(sc) : 0.f;
        const float et = e * tw;
        q0 += e; q1 += et;
        q2 = fmaf(et, v4.x, q2); q3 = fmaf(et, v4.y, q3);
        q4 = fmaf(et, v4.z, q4); q5 = fmaf(et, v4.w, q5);
        q6 = fmaf(et, vb.x, q6); q7 = fmaf(et, vb.y, q7);
      }
    }

    // ---- reduction: 8 independent DPP prefix-sums (VALU-only, no DS pipe),
    // totals read from lane 63 into SGPRs ----
    const float Se  = total63(q0);
    const float Set = total63(q1);
    const float T2  = total63(q2);
    const float T3  = total63(q3);
    const float T4  = total63(q4);
    const float T5  = total63(q5);
    const float T6  = total63(q6);
    const float T7  = total63(q7);

    const float denom = Se + 1e-8f;
    const float ws = fmaxf(Set / denom, 1e-8f);
    const float scale = 1.0f / (denom * ws);  // one div (uniform) vs 12 lane-divs
    if (lane >= 2 && lane < 8) {
      float num = T2;
      num = (lane == 3) ? T3 : num;
      num = (lane == 4) ? T4 : num;
      num = (lane == 5) ? T5 : num;
      num = (lane == 6) ? T6 : num;
      num = (lane == 7) ? T7 : num;
      out[(size_t)b * (NROLE * NDIM) + r * NDIM + (lane - 2)] = num * scale;
    }
  }
}

extern "C" void kernel_launch(void* const* d_in, const int* in_sizes, int n_in,
                              void* d_out, int out_size, void* d_ws, size_t ws_size,
                              hipStream_t stream) {
  const float* states = (const float*)d_in[0];
  const int* roles = (const int*)d_in[1];
  const int* maskp = (const int*)d_in[2];
  const float* trust = (const float*)d_in[3];
  const float* W1 = (const float*)d_in[4];
  const float* b1 = (const float*)d_in[5];
  const float* W2 = (const float*)d_in[6];
  const float* b2 = (const float*)d_in[7];
  float* out = (float*)d_out;

  hmf_main<<<NBATCH, 192, 0, stream>>>(states, roles, maskp, trust, W1, b1, W2, b2, out);
}